// Round 1
// baseline (252.545 us; speedup 1.0000x reference)
//
#include <hip/hip_runtime.h>
#include <hip/hip_bf16.h>
#include <math.h>

#define S_LEN   1024
#define BATCH   4
#define NHEAD   16
#define DHEAD   6
#define DMODEL  192
#define INNER   96

// ---------------- helpers ----------------
__device__ __forceinline__ float bf2f(unsigned int u) {
    union { unsigned int i; float f; } c; c.i = u; return c.f;
}

// ---------------- kernel 1: phi = r @ r_kernel, bf16, rows padded to 8 ----------------
// phiB layout: [n][t][8] bf16, t in [0,2048)
__global__ void k_phi(const float* __restrict__ r_kernel, unsigned short* __restrict__ phiB) {
    __shared__ float r_row[DMODEL];
    int t = blockIdx.x;          // 0..2047
    int tid = threadIdx.x;       // 0..191
    float rel = (float)(S_LEN - t);
    if (tid < 96) {
        float w = powf(10000.0f, -(float)tid * (1.0f / 96.0f));
        r_row[tid] = sinf(rel * w);
    } else {
        float w = powf(10000.0f, -(float)(tid - 96) * (1.0f / 96.0f));
        r_row[tid] = cosf(rel * w);
    }
    __syncthreads();
    if (tid < 96) {
        float acc = 0.f;
        #pragma unroll 4
        for (int d = 0; d < DMODEL; ++d) acc += r_row[d] * r_kernel[d * 96 + tid];
        int n = tid / 6, h = tid - n * 6;
        __hip_bfloat16 bvv = __float2bfloat16(acc);
        phiB[(n * 2048 + t) * 8 + h] = *(unsigned short*)&bvv;
    } else if (tid < 128) {
        int p = tid - 96; int n = p >> 1; int h = 6 + (p & 1);
        phiB[(n * 2048 + t) * 8 + h] = 0;   // zero the pad lanes
    }
}

// ---------------- kernel 2: QKV projections ----------------
// outputs: QW,QR,K,V each [b][n][s][6] f32
__global__ void k_qkv(const float* __restrict__ x,
                      const float* __restrict__ Wq, const float* __restrict__ Wk,
                      const float* __restrict__ bk, const float* __restrict__ Wv,
                      const float* __restrict__ bv,
                      const float* __restrict__ rwb, const float* __restrict__ rrb,
                      float* __restrict__ QW, float* __restrict__ QR,
                      float* __restrict__ Ko, float* __restrict__ Vo) {
    __shared__ float xs[8 * 194];           // 8 rows padded to 194 (bank spread)
    int tid = threadIdx.x;                  // 0..191
    int row0 = blockIdx.x * 8;
    for (int idx = tid; idx < 8 * 192; idx += 192) {
        int r = idx / 192, c = idx - r * 192;
        xs[r * 194 + c] = x[(size_t)(row0 + r) * 192 + c];
    }
    __syncthreads();
    int rl = tid / 24, cq = tid - rl * 24, c0 = cq * 4;
    float4 aq = {0,0,0,0}, ak = {0,0,0,0}, av = {0,0,0,0};
    const float* xr = &xs[rl * 194];
    #pragma unroll 2
    for (int d = 0; d < 192; ++d) {
        float xd = xr[d];
        float4 wq = *(const float4*)&Wq[d * 96 + c0];
        float4 wk = *(const float4*)&Wk[d * 96 + c0];
        float4 wv = *(const float4*)&Wv[d * 96 + c0];
        aq.x += xd * wq.x; aq.y += xd * wq.y; aq.z += xd * wq.z; aq.w += xd * wq.w;
        ak.x += xd * wk.x; ak.y += xd * wk.y; ak.z += xd * wk.z; ak.w += xd * wk.w;
        av.x += xd * wv.x; av.y += xd * wv.y; av.z += xd * wv.z; av.w += xd * wv.w;
    }
    int row = row0 + rl; int b = row >> 10; int s = row & 1023;
    const float is6 = 0.4082482904638630f;  // 1/sqrt(6)
    float qv[4] = {aq.x, aq.y, aq.z, aq.w};
    float kv[4] = {ak.x, ak.y, ak.z, ak.w};
    float vv[4] = {av.x, av.y, av.z, av.w};
    #pragma unroll
    for (int cc = 0; cc < 4; ++cc) {
        int c = c0 + cc; int n = c / 6; int h = c - n * 6;
        size_t o = ((size_t)(b * 16 + n) * 1024 + s) * 6 + h;
        float q = qv[cc] * is6;
        QW[o] = q + rwb[c] * is6;
        QR[o] = q + rrb[c] * is6;
        Ko[o] = kv[cc] + bk[c];
        Vo[o] = vv[cc] + bv[c];
    }
}

// ---------------- kernel 3: fused attention ----------------
// grid (S/256, NHEAD, BATCH), block 256; thread = one query row.
__global__ __launch_bounds__(256)
void k_attn(const float* __restrict__ QW, const float* __restrict__ QR,
            const float* __restrict__ Kk, const float* __restrict__ Vv,
            const unsigned short* __restrict__ phiB,
            const float* __restrict__ mask,
            float* __restrict__ AV) {
    __shared__ uint4 phiS[1280];            // 1279 phi rows of 8 bf16 (16B each)
    int tid = threadIdx.x;
    int i0 = blockIdx.x * 256;
    int n = blockIdx.y, b = blockIdx.z;
    int tmin = S_LEN - i0 - 255;            // lowest phi row needed
    const uint4* phg = (const uint4*)phiB + (n * 2048 + tmin);
    for (int r = tid; r < 1279; r += 256) phiS[r] = phg[r];
    __syncthreads();

    int base = (b * 16 + n) * 1024;
    const float* qwp = QW + (size_t)(base + i0 + tid) * 6;
    const float* qrp = QR + (size_t)(base + i0 + tid) * 6;
    float qw0 = qwp[0], qw1 = qwp[1], qw2 = qwp[2], qw3 = qwp[3], qw4 = qwp[4], qw5 = qwp[5];
    float qr0 = qrp[0], qr1 = qrp[1], qr2 = qrp[2], qr3 = qrp[3], qr4 = qrp[4], qr5 = qrp[5];
    const float* Kp = Kk + (size_t)base * 6;
    const float* Vp = Vv + (size_t)base * 6;
    const float* mrow = mask + b * 1024;

    float denom = 0.f;
    float a0 = 0.f, a1 = 0.f, a2 = 0.f, a3 = 0.f, a4 = 0.f, a5 = 0.f;
    int rbase = 255 - tid;

    #pragma unroll 4
    for (int j = 0; j < 1024; ++j) {
        float2 k01 = *(const float2*)(Kp + j * 6);
        float2 k23 = *(const float2*)(Kp + j * 6 + 2);
        float2 k45 = *(const float2*)(Kp + j * 6 + 4);
        float2 v01 = *(const float2*)(Vp + j * 6);
        float2 v23 = *(const float2*)(Vp + j * 6 + 2);
        float2 v45 = *(const float2*)(Vp + j * 6 + 4);
        float mterm = 1e6f * (mrow[j] - 1.0f);
        uint4 ph = phiS[rbase + j];
        float p0 = bf2f(ph.x << 16), p1 = bf2f(ph.x & 0xffff0000u);
        float p2 = bf2f(ph.y << 16), p3 = bf2f(ph.y & 0xffff0000u);
        float p4 = bf2f(ph.z << 16), p5 = bf2f(ph.z & 0xffff0000u);
        float sc = qw0 * k01.x + qw1 * k01.y + qw2 * k23.x + qw3 * k23.y
                 + qw4 * k45.x + qw5 * k45.y
                 + qr0 * p0 + qr1 * p1 + qr2 * p2 + qr3 * p3 + qr4 * p4 + qr5 * p5
                 + mterm;
        float p = __expf(sc);               // scores bounded; masked -> exp underflows to 0
        denom += p;
        a0 += p * v01.x; a1 += p * v01.y; a2 += p * v23.x;
        a3 += p * v23.y; a4 += p * v45.x; a5 += p * v45.y;
    }
    float inv = 1.0f / denom;
    float* o = AV + (size_t)(b * 1024 + i0 + tid) * 96 + n * 6;
    o[0] = a0 * inv; o[1] = a1 * inv; o[2] = a2 * inv;
    o[3] = a3 * inv; o[4] = a4 * inv; o[5] = a5 * inv;
}

// ---------------- kernel 4: output projection + residual + LayerNorm ----------------
// one wave per row; lanes 0..47 each own 4 of the 192 output dims.
__global__ __launch_bounds__(256)
void k_out(const float* __restrict__ AV, const float* __restrict__ Wo,
           const float* __restrict__ bo, const float* __restrict__ x,
           const float* __restrict__ gamma, const float* __restrict__ beta,
           float* __restrict__ out) {
    int lane = threadIdx.x & 63, wv = threadIdx.x >> 6;
    int row = blockIdx.x * 4 + wv;
    const float* av = AV + (size_t)row * 96;
    float4 acc = {0,0,0,0};
    int d0 = lane * 4;
    bool active = lane < 48;
    if (active) {
        float4 bq = *(const float4*)&bo[d0];
        float4 xq = *(const float4*)&x[(size_t)row * 192 + d0];
        acc.x = bq.x + xq.x; acc.y = bq.y + xq.y; acc.z = bq.z + xq.z; acc.w = bq.w + xq.w;
        #pragma unroll 4
        for (int c = 0; c < 96; ++c) {
            float a = av[c];
            float4 w = *(const float4*)&Wo[c * 192 + d0];
            acc.x += a * w.x; acc.y += a * w.y; acc.z += a * w.z; acc.w += a * w.w;
        }
    }
    float sum = active ? (acc.x + acc.y + acc.z + acc.w) : 0.f;
    #pragma unroll
    for (int off = 32; off; off >>= 1) sum += __shfl_xor(sum, off, 64);
    float mu = sum * (1.0f / 192.0f);
    float dx = acc.x - mu, dy = acc.y - mu, dz = acc.z - mu, dw = acc.w - mu;
    float vs = active ? (dx * dx + dy * dy + dz * dz + dw * dw) : 0.f;
    #pragma unroll
    for (int off = 32; off; off >>= 1) vs += __shfl_xor(vs, off, 64);
    float rstd = rsqrtf(vs * (1.0f / 192.0f) + 1e-9f);
    if (active) {
        float4 g = *(const float4*)&gamma[d0];
        float4 bb = *(const float4*)&beta[d0];
        float4 r;
        r.x = dx * rstd * g.x + bb.x;
        r.y = dy * rstd * g.y + bb.y;
        r.z = dz * rstd * g.z + bb.z;
        r.w = dw * rstd * g.w + bb.w;
        *(float4*)&out[(size_t)row * 192 + d0] = r;
    }
}

// ---------------- launch ----------------
extern "C" void kernel_launch(void* const* d_in, const int* in_sizes, int n_in,
                              void* d_out, int out_size, void* d_ws, size_t ws_size,
                              hipStream_t stream) {
    const float* x        = (const float*)d_in[0];
    const float* mask0    = (const float*)d_in[1];
    const float* Wq       = (const float*)d_in[2];
    const float* Wk       = (const float*)d_in[3];
    const float* bk       = (const float*)d_in[4];
    const float* Wv       = (const float*)d_in[5];
    const float* bv       = (const float*)d_in[6];
    const float* Wo       = (const float*)d_in[7];
    const float* bo       = (const float*)d_in[8];
    const float* rwb      = (const float*)d_in[9];
    const float* rrb      = (const float*)d_in[10];
    const float* r_kernel = (const float*)d_in[11];
    const float* gamma    = (const float*)d_in[12];
    const float* beta     = (const float*)d_in[13];
    float* out = (float*)d_out;

    float* wsf = (float*)d_ws;
    float* QW = wsf;                       // 4*16*1024*6 = 393216
    float* QR = wsf + 393216;
    float* Kk = wsf + 786432;
    float* Vv = wsf + 1179648;
    float* AV = wsf + 1572864;             // [4096][96]
    unsigned short* phiB = (unsigned short*)(wsf + 1966080);  // [16][2048][8] bf16

    k_phi<<<2048, 192, 0, stream>>>(r_kernel, phiB);
    k_qkv<<<512, 192, 0, stream>>>(x, Wq, Wk, bk, Wv, bv, rwb, rrb, QW, QR, Kk, Vv);
    k_attn<<<dim3(4, 16, 4), 256, 0, stream>>>(QW, QR, Kk, Vv, phiB, mask0, AV);
    k_out<<<1024, 256, 0, stream>>>(AV, Wo, bo, x, gamma, beta, out);
}

// Round 2
// 159.597 us; speedup vs baseline: 1.5824x; 1.5824x over previous
//
#include <hip/hip_runtime.h>
#include <hip/hip_bf16.h>
#include <math.h>

#define S_LEN   1024
#define BATCH   4
#define NHEAD   16
#define DHEAD   6
#define DMODEL  192
#define INNER   96

// ---------------- helpers ----------------
__device__ __forceinline__ float bf2f(unsigned int u) {
    union { unsigned int i; float f; } c; c.i = u; return c.f;
}

// ---------------- kernel 1: phi = r @ r_kernel, bf16, rows padded to 8 ----------------
// phiB layout: [n][t][8] bf16, t in [0,2048)
__global__ void k_phi(const float* __restrict__ r_kernel, unsigned short* __restrict__ phiB) {
    __shared__ float r_row[DMODEL];
    int t = blockIdx.x;          // 0..2047
    int tid = threadIdx.x;       // 0..191
    float rel = (float)(S_LEN - t);
    if (tid < 96) {
        float w = powf(10000.0f, -(float)tid * (1.0f / 96.0f));
        r_row[tid] = sinf(rel * w);
    } else {
        float w = powf(10000.0f, -(float)(tid - 96) * (1.0f / 96.0f));
        r_row[tid] = cosf(rel * w);
    }
    __syncthreads();
    if (tid < 96) {
        float acc = 0.f;
        #pragma unroll 4
        for (int d = 0; d < DMODEL; ++d) acc += r_row[d] * r_kernel[d * 96 + tid];
        int n = tid / 6, h = tid - n * 6;
        __hip_bfloat16 bvv = __float2bfloat16(acc);
        phiB[(n * 2048 + t) * 8 + h] = *(unsigned short*)&bvv;
    } else if (tid < 128) {
        int p = tid - 96; int n = p >> 1; int h = 6 + (p & 1);
        phiB[(n * 2048 + t) * 8 + h] = 0;   // zero the pad lanes
    }
}

// ---------------- kernel 2: QKV projections ----------------
// outputs: QWt,QRt as [b][n][h][s] f32 (coalesced q loads in k_attn);
//          KVM as [b][n][s][16] f32: k0..5, v0..5, mterm, pad3
__global__ void k_qkv(const float* __restrict__ x,
                      const float* __restrict__ Wq, const float* __restrict__ Wk,
                      const float* __restrict__ bk, const float* __restrict__ Wv,
                      const float* __restrict__ bv,
                      const float* __restrict__ rwb, const float* __restrict__ rrb,
                      const float* __restrict__ mask,
                      float* __restrict__ QWt, float* __restrict__ QRt,
                      float* __restrict__ KVM) {
    __shared__ float xs[8 * 194];           // 8 rows padded to 194
    int tid = threadIdx.x;                  // 0..191
    int row0 = blockIdx.x * 8;
    for (int idx = tid; idx < 8 * 192; idx += 192) {
        int r = idx / 192, c = idx - r * 192;
        xs[r * 194 + c] = x[(size_t)(row0 + r) * 192 + c];
    }
    __syncthreads();
    int rl = tid / 24, cq = tid - rl * 24, c0 = cq * 4;
    float4 aq = {0,0,0,0}, ak = {0,0,0,0}, av = {0,0,0,0};
    const float* xr = &xs[rl * 194];
    #pragma unroll 2
    for (int d = 0; d < 192; ++d) {
        float xd = xr[d];
        float4 wq = *(const float4*)&Wq[d * 96 + c0];
        float4 wk = *(const float4*)&Wk[d * 96 + c0];
        float4 wv = *(const float4*)&Wv[d * 96 + c0];
        aq.x += xd * wq.x; aq.y += xd * wq.y; aq.z += xd * wq.z; aq.w += xd * wq.w;
        ak.x += xd * wk.x; ak.y += xd * wk.y; ak.z += xd * wk.z; ak.w += xd * wk.w;
        av.x += xd * wv.x; av.y += xd * wv.y; av.z += xd * wv.z; av.w += xd * wv.w;
    }
    int row = row0 + rl; int b = row >> 10; int s = row & 1023;
    const float is6 = 0.4082482904638630f;  // 1/sqrt(6)
    float qv[4] = {aq.x, aq.y, aq.z, aq.w};
    float kv[4] = {ak.x, ak.y, ak.z, ak.w};
    float vv[4] = {av.x, av.y, av.z, av.w};
    #pragma unroll
    for (int cc = 0; cc < 4; ++cc) {
        int c = c0 + cc; int n = c / 6; int h = c - n * 6;
        size_t qo = ((size_t)(b * 16 + n) * 6 + h) * 1024 + s;
        float q = qv[cc] * is6;
        QWt[qo] = q + rwb[c] * is6;
        QRt[qo] = q + rrb[c] * is6;
        size_t ko = ((size_t)(b * 16 + n) * 1024 + s) * 16;
        KVM[ko + h]     = kv[cc] + bk[c];
        KVM[ko + 6 + h] = vv[cc] + bv[c];
    }
    if (cq == 0) {
        float mterm = 1e6f * (mask[b * 1024 + s] - 1.0f);
        #pragma unroll
        for (int n = 0; n < 16; ++n)
            KVM[((size_t)(b * 16 + n) * 1024 + s) * 16 + 12] = mterm;
    }
}

// ---------------- kernel 3: fused attention, j-split by 4 ----------------
// grid (16, NHEAD, BATCH): blockIdx.x = ic + 4*jc. thread = one query row.
// Writes partial (denom, a0..a5) per (b,n,i,jc) to P.
__global__ __launch_bounds__(256)
void k_attn(const float* __restrict__ QWt, const float* __restrict__ QRt,
            const float* __restrict__ KVM,
            const unsigned short* __restrict__ phiB,
            float* __restrict__ P) {
    __shared__ uint4 phiS[511];
    int tid = threadIdx.x;
    int ic = blockIdx.x & 3, jc = blockIdx.x >> 2;
    int n = blockIdx.y, b = blockIdx.z;
    int i0 = ic * 256, j0 = jc * 256;
    int tmin = 769 - i0 + j0;               // lowest phi row needed
    const uint4* phg = (const uint4*)phiB + (n * 2048 + tmin);
    for (int r = tid; r < 511; r += 256) phiS[r] = phg[r];
    __syncthreads();

    int bn = b * 16 + n;
    int i = i0 + tid;
    const float* qwb = QWt + (size_t)bn * 6144 + i;
    const float* qrb = QRt + (size_t)bn * 6144 + i;
    float qw0 = qwb[0], qw1 = qwb[1024], qw2 = qwb[2048],
          qw3 = qwb[3072], qw4 = qwb[4096], qw5 = qwb[5120];
    float qr0 = qrb[0], qr1 = qrb[1024], qr2 = qrb[2048],
          qr3 = qrb[3072], qr4 = qrb[4096], qr5 = qrb[5120];
    const float* kvb = KVM + (size_t)bn * 16384 + (size_t)j0 * 16;

    float denom = 0.f;
    float a0 = 0.f, a1 = 0.f, a2 = 0.f, a3 = 0.f, a4 = 0.f, a5 = 0.f;
    int rbase = 255 - tid;

    #pragma unroll 4
    for (int jj = 0; jj < 256; ++jj) {
        const float* kvr = kvb + jj * 16;   // wave-uniform address -> s_load
        float k0 = kvr[0], k1 = kvr[1], k2 = kvr[2];
        float k3 = kvr[3], k4 = kvr[4], k5 = kvr[5];
        float v0 = kvr[6], v1 = kvr[7], v2 = kvr[8];
        float v3 = kvr[9], v4 = kvr[10], v5 = kvr[11];
        float mterm = kvr[12];
        uint4 ph = phiS[rbase + jj];
        float p0 = bf2f(ph.x << 16), p1 = bf2f(ph.x & 0xffff0000u);
        float p2 = bf2f(ph.y << 16), p3 = bf2f(ph.y & 0xffff0000u);
        float p4 = bf2f(ph.z << 16), p5 = bf2f(ph.z & 0xffff0000u);
        float sA = qw0 * k0 + qw1 * k1 + qw2 * k2;
        float sB = qw3 * k3 + qw4 * k4 + qw5 * k5;
        float sC = qr0 * p0 + qr1 * p1 + qr2 * p2;
        float sD = qr3 * p3 + qr4 * p4 + qr5 * p5;
        float sc = (sA + sB) + (sC + sD) + mterm;
        float p = __expf(sc);
        denom += p;
        a0 += p * v0; a1 += p * v1; a2 += p * v2;
        a3 += p * v3; a4 += p * v4; a5 += p * v5;
    }
    float4* po = (float4*)(P + ((size_t)bn * 1024 + i) * 32 + jc * 8);
    po[0] = make_float4(denom, a0, a1, a2);
    po[1] = make_float4(a3, a4, a5, 0.f);
}

// ---------------- kernel 3b: combine j-chunks, normalize ----------------
__global__ __launch_bounds__(256)
void k_comb(const float* __restrict__ P, float* __restrict__ AV) {
    int flat = blockIdx.x * 256 + threadIdx.x;       // (b*16+n)*1024 + i
    int b = flat >> 14, rem = flat & 16383, n = rem >> 10, i = rem & 1023;
    const float4* p = (const float4*)(P + (size_t)flat * 32);
    float denom = 0.f, a0 = 0.f, a1 = 0.f, a2 = 0.f, a3 = 0.f, a4 = 0.f, a5 = 0.f;
    #pragma unroll
    for (int jc = 0; jc < 4; ++jc) {
        float4 u = p[jc * 2], w = p[jc * 2 + 1];
        denom += u.x; a0 += u.y; a1 += u.z; a2 += u.w;
        a3 += w.x; a4 += w.y; a5 += w.z;
    }
    float inv = 1.0f / denom;
    float* o = AV + (size_t)(b * 1024 + i) * 96 + n * 6;
    o[0] = a0 * inv; o[1] = a1 * inv; o[2] = a2 * inv;
    o[3] = a3 * inv; o[4] = a4 * inv; o[5] = a5 * inv;
}

// ---------------- kernel 4: output projection + residual + LayerNorm ----------------
__global__ __launch_bounds__(256)
void k_out(const float* __restrict__ AV, const float* __restrict__ Wo,
           const float* __restrict__ bo, const float* __restrict__ x,
           const float* __restrict__ gamma, const float* __restrict__ beta,
           float* __restrict__ out) {
    int lane = threadIdx.x & 63, wv = threadIdx.x >> 6;
    int row = blockIdx.x * 4 + wv;
    const float* av = AV + (size_t)row * 96;
    float4 acc = {0,0,0,0};
    int d0 = lane * 4;
    bool active = lane < 48;
    if (active) {
        float4 bq = *(const float4*)&bo[d0];
        float4 xq = *(const float4*)&x[(size_t)row * 192 + d0];
        acc.x = bq.x + xq.x; acc.y = bq.y + xq.y; acc.z = bq.z + xq.z; acc.w = bq.w + xq.w;
        #pragma unroll 4
        for (int c = 0; c < 96; ++c) {
            float a = av[c];
            float4 w = *(const float4*)&Wo[c * 192 + d0];
            acc.x += a * w.x; acc.y += a * w.y; acc.z += a * w.z; acc.w += a * w.w;
        }
    }
    float sum = active ? (acc.x + acc.y + acc.z + acc.w) : 0.f;
    #pragma unroll
    for (int off = 32; off; off >>= 1) sum += __shfl_xor(sum, off, 64);
    float mu = sum * (1.0f / 192.0f);
    float dx = acc.x - mu, dy = acc.y - mu, dz = acc.z - mu, dw = acc.w - mu;
    float vs = active ? (dx * dx + dy * dy + dz * dz + dw * dw) : 0.f;
    #pragma unroll
    for (int off = 32; off; off >>= 1) vs += __shfl_xor(vs, off, 64);
    float rstd = rsqrtf(vs * (1.0f / 192.0f) + 1e-9f);
    if (active) {
        float4 g = *(const float4*)&gamma[d0];
        float4 bb = *(const float4*)&beta[d0];
        float4 r;
        r.x = dx * rstd * g.x + bb.x;
        r.y = dy * rstd * g.y + bb.y;
        r.z = dz * rstd * g.z + bb.z;
        r.w = dw * rstd * g.w + bb.w;
        *(float4*)&out[(size_t)row * 192 + d0] = r;
    }
}

// ---------------- launch ----------------
extern "C" void kernel_launch(void* const* d_in, const int* in_sizes, int n_in,
                              void* d_out, int out_size, void* d_ws, size_t ws_size,
                              hipStream_t stream) {
    const float* x        = (const float*)d_in[0];
    const float* mask0    = (const float*)d_in[1];
    const float* Wq       = (const float*)d_in[2];
    const float* Wk       = (const float*)d_in[3];
    const float* bk       = (const float*)d_in[4];
    const float* Wv       = (const float*)d_in[5];
    const float* bv       = (const float*)d_in[6];
    const float* Wo       = (const float*)d_in[7];
    const float* bo       = (const float*)d_in[8];
    const float* rwb      = (const float*)d_in[9];
    const float* rrb      = (const float*)d_in[10];
    const float* r_kernel = (const float*)d_in[11];
    const float* gamma    = (const float*)d_in[12];
    const float* beta     = (const float*)d_in[13];
    float* out = (float*)d_out;

    float* wsf = (float*)d_ws;
    float* QWt = wsf;                                 // 393216
    float* QRt = wsf + 393216;                        // 393216
    float* KVM = wsf + 786432;                        // 1048576
    float* P   = wsf + 1835008;                       // 2097152
    float* AV  = wsf + 3932160;                       // 393216
    unsigned short* phiB = (unsigned short*)(wsf + 4325376);  // 262144 ushorts

    k_phi<<<2048, 192, 0, stream>>>(r_kernel, phiB);
    k_qkv<<<512, 192, 0, stream>>>(x, Wq, Wk, bk, Wv, bv, rwb, rrb, mask0,
                                   QWt, QRt, KVM);
    k_attn<<<dim3(16, 16, 4), 256, 0, stream>>>(QWt, QRt, KVM, phiB, P);
    k_comb<<<256, 256, 0, stream>>>(P, AV);
    k_out<<<1024, 256, 0, stream>>>(AV, Wo, bo, x, gamma, beta, out);
}

// Round 4
// 156.185 us; speedup vs baseline: 1.6170x; 1.0219x over previous
//
#include <hip/hip_runtime.h>
#include <hip/hip_bf16.h>
#include <math.h>

#define LOG2E 1.4426950408889634f
#define IS6   0.4082482904638630f

typedef _Float16 h2 __attribute__((ext_vector_type(2)));

#if defined(__has_builtin)
#if __has_builtin(__builtin_amdgcn_fdot2)
#define FDOT2(a,b,c) __builtin_amdgcn_fdot2((a),(b),(c),false)
#endif
#endif
#ifndef FDOT2
#define FDOT2(a,b,c) ((float)(a).x*(float)(b).x + (float)(a).y*(float)(b).y + (c))
#endif

__device__ __forceinline__ unsigned packh2(float x, float y) {
    h2 v; v.x = (_Float16)x; v.y = (_Float16)y;
    return *(unsigned*)&v;
}
__device__ __forceinline__ h2 ash2(unsigned u) { return *(h2*)&u; }

// ---------------- kernel 1: phi[n][t][h] f16 (rows padded to 8) ----------------
__global__ __launch_bounds__(192)
void k_phi(const float* __restrict__ rk, unsigned short* __restrict__ phiB) {
    __shared__ float rkS[96 * 96];
    __shared__ float rrowS[8 * 192];
    int tid = threadIdx.x;
    int t0 = blockIdx.x * 8;
    {
        int d = tid;
        int dd = d < 96 ? d : d - 96;
        float w = exp2f(-(float)dd * 0.13841367062030676f);  // log2(10000)/96
        #pragma unroll
        for (int tl = 0; tl < 8; ++tl) {
            float rel = (float)(1024 - (t0 + tl));
            float ang = rel * w;
            rrowS[tl * 192 + d] = (d < 96) ? sinf(ang) : cosf(ang);
        }
    }
    float acc0 = 0.f, acc1 = 0.f, acc2 = 0.f, acc3 = 0.f;
    int c = tid % 96, tg = tid / 96;
    for (int ph = 0; ph < 2; ++ph) {
        __syncthreads();
        for (int idx = tid; idx < 9216; idx += 192) rkS[idx] = rk[ph * 9216 + idx];
        __syncthreads();
        for (int dr = 0; dr < 96; dr += 4) {
            float4 r0 = *(float4*)&rrowS[(tg * 4 + 0) * 192 + ph * 96 + dr];
            float4 r1 = *(float4*)&rrowS[(tg * 4 + 1) * 192 + ph * 96 + dr];
            float4 r2 = *(float4*)&rrowS[(tg * 4 + 2) * 192 + ph * 96 + dr];
            float4 r3 = *(float4*)&rrowS[(tg * 4 + 3) * 192 + ph * 96 + dr];
            float k0 = rkS[(dr + 0) * 96 + c];
            float k1 = rkS[(dr + 1) * 96 + c];
            float k2 = rkS[(dr + 2) * 96 + c];
            float k3 = rkS[(dr + 3) * 96 + c];
            acc0 += r0.x * k0 + r0.y * k1 + r0.z * k2 + r0.w * k3;
            acc1 += r1.x * k0 + r1.y * k1 + r1.z * k2 + r1.w * k3;
            acc2 += r2.x * k0 + r2.y * k1 + r2.z * k2 + r2.w * k3;
            acc3 += r3.x * k0 + r3.y * k1 + r3.z * k2 + r3.w * k3;
        }
    }
    int n = c / 6, h = c - n * 6;
    float av[4] = {acc0, acc1, acc2, acc3};
    #pragma unroll
    for (int k = 0; k < 4; ++k) {
        int t = t0 + tg * 4 + k;
        _Float16 v = (_Float16)av[k];
        phiB[(n * 2048 + t) * 8 + h] = *(unsigned short*)&v;
    }
    if (tg == 0 && c < 32) {
        int nn = c >> 1, hh = 6 + (c & 1);
        #pragma unroll
        for (int k = 0; k < 8; ++k) phiB[(nn * 2048 + t0 + k) * 8 + hh] = 0;
    }
}

// ---------------- kernel 2: QKV projections ----------------
// QWt/QRt: [bn][hp][s] f16x2, pre-scaled by 1/sqrt(6) and log2(e), biases folded.
// KVM row (16 dwords, 64B): [k01,k23,k45, mterm*log2e, v0..v5 f32, pads zeroed]
__global__ __launch_bounds__(192)
void k_qkv(const float* __restrict__ x,
           const float* __restrict__ Wq, const float* __restrict__ Wk,
           const float* __restrict__ bk, const float* __restrict__ Wv,
           const float* __restrict__ bv,
           const float* __restrict__ rwb, const float* __restrict__ rrb,
           const float* __restrict__ mask,
           unsigned* __restrict__ QWt, unsigned* __restrict__ QRt,
           unsigned* __restrict__ KVM) {
    __shared__ float xs[16 * 194];
    int tid = threadIdx.x;
    int row0 = blockIdx.x * 16;
    for (int idx = tid; idx < 16 * 192; idx += 192) {
        int r = idx / 192, cc = idx - r * 192;
        xs[r * 194 + cc] = x[(size_t)(row0 + r) * 192 + cc];
    }
    __syncthreads();
    int ct = tid % 24, rg = tid / 24, c0 = ct * 4;
    float aq[2][4] = {{0,0,0,0},{0,0,0,0}};
    float ak[2][4] = {{0,0,0,0},{0,0,0,0}};
    float av[2][4] = {{0,0,0,0},{0,0,0,0}};
    const float* x0 = &xs[(rg * 2 + 0) * 194];
    const float* x1 = &xs[(rg * 2 + 1) * 194];
    for (int d = 0; d < 192; ++d) {
        float4 wq = *(const float4*)&Wq[d * 96 + c0];
        float4 wk = *(const float4*)&Wk[d * 96 + c0];
        float4 wv = *(const float4*)&Wv[d * 96 + c0];
        float xa = x0[d], xb = x1[d];
        aq[0][0] += xa * wq.x; aq[0][1] += xa * wq.y; aq[0][2] += xa * wq.z; aq[0][3] += xa * wq.w;
        ak[0][0] += xa * wk.x; ak[0][1] += xa * wk.y; ak[0][2] += xa * wk.z; ak[0][3] += xa * wk.w;
        av[0][0] += xa * wv.x; av[0][1] += xa * wv.y; av[0][2] += xa * wv.z; av[0][3] += xa * wv.w;
        aq[1][0] += xb * wq.x; aq[1][1] += xb * wq.y; aq[1][2] += xb * wq.z; aq[1][3] += xb * wq.w;
        ak[1][0] += xb * wk.x; ak[1][1] += xb * wk.y; ak[1][2] += xb * wk.z; ak[1][3] += xb * wk.w;
        av[1][0] += xb * wv.x; av[1][1] += xb * wv.y; av[1][2] += xb * wv.z; av[1][3] += xb * wv.w;
    }
    #pragma unroll
    for (int rr = 0; rr < 2; ++rr) {
        int row = row0 + rg * 2 + rr;
        int b = row >> 10, s = row & 1023;
        #pragma unroll
        for (int pp = 0; pp < 2; ++pp) {
            int pg = (c0 >> 1) + pp;
            int n = pg / 3, hp = pg - n * 3;
            int cA = c0 + 2 * pp;
            float qA = aq[rr][2 * pp] * IS6, qB = aq[rr][2 * pp + 1] * IS6;
            unsigned qwp = packh2((qA + rwb[cA] * IS6) * LOG2E, (qB + rwb[cA + 1] * IS6) * LOG2E);
            unsigned qrp = packh2((qA + rrb[cA] * IS6) * LOG2E, (qB + rrb[cA + 1] * IS6) * LOG2E);
            size_t qo = ((size_t)((b * 16 + n) * 3 + hp)) * 1024 + s;
            QWt[qo] = qwp;
            QRt[qo] = qrp;
            unsigned kp = packh2(ak[rr][2 * pp] + bk[cA], ak[rr][2 * pp + 1] + bk[cA + 1]);
            size_t ko = ((size_t)(b * 16 + n) * 1024 + s) * 16;
            KVM[ko + hp] = kp;
            KVM[ko + 4 + 2 * hp] = __float_as_uint(av[rr][2 * pp] + bv[cA]);
            KVM[ko + 5 + 2 * hp] = __float_as_uint(av[rr][2 * pp + 1] + bv[cA + 1]);
        }
        if (ct == 0) {
            float m = 1e6f * (mask[b * 1024 + s] - 1.0f) * LOG2E;
            #pragma unroll
            for (int n = 0; n < 16; ++n) {
                size_t ko = ((size_t)(b * 16 + n) * 1024 + s) * 16;
                KVM[ko + 3] = __float_as_uint(m);
                // zero the pad dwords so every byte of KVM is written each call
                KVM[ko + 10] = 0; KVM[ko + 11] = 0; KVM[ko + 12] = 0;
                KVM[ko + 13] = 0; KVM[ko + 14] = 0; KVM[ko + 15] = 0;
            }
        }
    }
}

// ---------------- kernel 3: fused attention, j-split 4, KV staged in LDS ----------------
// grid (16,16,4): bx = ic + 4*jc. thread = one query row; 256 j per block.
// f32 partials (denom, a0..a5) -> P[jc][bn][i][8]
__global__ __launch_bounds__(256)
void k_attn(const unsigned* __restrict__ QWt, const unsigned* __restrict__ QRt,
            const unsigned* __restrict__ KVM,
            const unsigned short* __restrict__ phiB,
            float4* __restrict__ P) {
    __shared__ uint4 phiS[511];      // 8176 B
    __shared__ uint4 kvS[1024];      // 16384 B : 256 rows x 4 uint4
    int tid = threadIdx.x;
    int ic = blockIdx.x & 3, jc = blockIdx.x >> 2;
    int n = blockIdx.y, b = blockIdx.z;
    int i0 = ic * 256, j0 = jc * 256;
    int bn = b * 16 + n;

    int tmin = 769 - i0 + j0;
    const uint4* phg = (const uint4*)phiB + (n * 2048 + tmin);
    for (int r = tid; r < 511; r += 256) phiS[r] = phg[r];
    const uint4* kvg = (const uint4*)KVM + ((size_t)bn * 1024 + j0) * 4;
    #pragma unroll
    for (int r = 0; r < 4; ++r) kvS[r * 256 + tid] = kvg[r * 256 + tid];
    __syncthreads();

    size_t qb = (size_t)bn * 3072 + i0 + tid;
    h2 qw01 = ash2(QWt[qb]), qw23 = ash2(QWt[qb + 1024]), qw45 = ash2(QWt[qb + 2048]);
    h2 qr01 = ash2(QRt[qb]), qr23 = ash2(QRt[qb + 1024]), qr45 = ash2(QRt[qb + 2048]);

    float denom = 0.f;
    float a0 = 0.f, a1 = 0.f, a2 = 0.f, a3 = 0.f, a4 = 0.f, a5 = 0.f;
    int rbase = 255 - tid;

    #pragma unroll 4
    for (int jj = 0; jj < 256; ++jj) {
        uint4 A = kvS[jj * 4];          // wave-uniform -> LDS broadcast
        uint4 B = kvS[jj * 4 + 1];
        uint4 C = kvS[jj * 4 + 2];
        uint4 ph = phiS[rbase + jj];
        float sc = FDOT2(ash2(A.x), qw01,
                   FDOT2(ash2(A.y), qw23,
                   FDOT2(ash2(A.z), qw45, __uint_as_float(A.w))));
        sc = FDOT2(ash2(ph.x), qr01,
             FDOT2(ash2(ph.y), qr23,
             FDOT2(ash2(ph.z), qr45, sc)));
        float p = exp2f(sc);
        denom += p;
        a0 += p * __uint_as_float(B.x); a1 += p * __uint_as_float(B.y);
        a2 += p * __uint_as_float(B.z); a3 += p * __uint_as_float(B.w);
        a4 += p * __uint_as_float(C.x); a5 += p * __uint_as_float(C.y);
    }
    size_t pb = ((((size_t)(jc * 64 + bn)) << 10) + i0 + tid) * 2;
    P[pb]     = make_float4(denom, a0, a1, a2);
    P[pb + 1] = make_float4(a3, a4, a5, 0.f);
}

// ---------------- kernel 4: combine + Wo projection + residual + LayerNorm ----------------
// 512 blocks x 256 threads, 8 rows/block.
__global__ __launch_bounds__(256)
void k_out(const float4* __restrict__ P, const float* __restrict__ Wo,
           const float* __restrict__ bo, const float* __restrict__ x,
           const float* __restrict__ gamma, const float* __restrict__ beta,
           float* __restrict__ out) {
    __shared__ unsigned WoS[96 * 96];   // 36864 B
    __shared__ float avS[8 * 96];       // 3072 B
    int tid = threadIdx.x;
    int row0 = blockIdx.x * 8;
    for (int idx = tid; idx < 9216; idx += 256) {
        int c = idx / 96, pd = idx - c * 96;
        float2 w = *(const float2*)&Wo[c * 192 + pd * 2];
        WoS[idx] = packh2(w.x, w.y);
    }
    if (tid < 128) {                    // combine 4 j-chunks for (row rl, head n)
        int rl = tid >> 4, n = tid & 15;
        int row = row0 + rl, b = row >> 10, i = row & 1023;
        int bn = b * 16 + n;
        float d = 0.f, s0 = 0.f, s1 = 0.f, s2 = 0.f, s3 = 0.f, s4 = 0.f, s5 = 0.f;
        #pragma unroll
        for (int jjc = 0; jjc < 4; ++jjc) {
            size_t pb = ((((size_t)(jjc * 64 + bn)) << 10) + i) * 2;
            float4 u = P[pb], v = P[pb + 1];
            d += u.x; s0 += u.y; s1 += u.z; s2 += u.w;
            s3 += v.x; s4 += v.y; s5 += v.z;
        }
        float inv = 1.0f / d;
        float* o = &avS[rl * 96 + n * 6];
        o[0] = s0 * inv; o[1] = s1 * inv; o[2] = s2 * inv;
        o[3] = s3 * inv; o[4] = s4 * inv; o[5] = s5 * inv;
    }
    __syncthreads();

    int lane = tid & 63, wv = tid >> 6;
    bool act = lane < 48;
    int d0 = lane * 4;
    #pragma unroll
    for (int rr = 0; rr < 2; ++rr) {
        int r = wv * 2 + rr, row = row0 + r;
        float ax = 0.f, ay = 0.f, az = 0.f, aw = 0.f;
        if (act) {
            float4 bq = *(const float4*)&bo[d0];
            float4 xq = *(const float4*)&x[(size_t)row * 192 + d0];
            ax = bq.x + xq.x; ay = bq.y + xq.y; az = bq.z + xq.z; aw = bq.w + xq.w;
            for (int c2 = 0; c2 < 96; ++c2) {
                float a = avS[r * 96 + c2];
                uint2 wp = *(uint2*)&WoS[c2 * 96 + lane * 2];
                h2 w0 = ash2(wp.x), w1 = ash2(wp.y);
                ax += a * (float)w0.x; ay += a * (float)w0.y;
                az += a * (float)w1.x; aw += a * (float)w1.y;
            }
        }
        float sum = act ? (ax + ay + az + aw) : 0.f;
        #pragma unroll
        for (int off = 32; off; off >>= 1) sum += __shfl_xor(sum, off, 64);
        float mu = sum * (1.0f / 192.0f);
        float dx = ax - mu, dy = ay - mu, dz = az - mu, dw = aw - mu;
        float vs = act ? (dx * dx + dy * dy + dz * dz + dw * dw) : 0.f;
        #pragma unroll
        for (int off = 32; off; off >>= 1) vs += __shfl_xor(vs, off, 64);
        float rstd = rsqrtf(vs * (1.0f / 192.0f) + 1e-9f);
        if (act) {
            float4 g = *(const float4*)&gamma[d0];
            float4 bb = *(const float4*)&beta[d0];
            float4 rv;
            rv.x = dx * rstd * g.x + bb.x;
            rv.y = dy * rstd * g.y + bb.y;
            rv.z = dz * rstd * g.z + bb.z;
            rv.w = dw * rstd * g.w + bb.w;
            *(float4*)&out[(size_t)row * 192 + d0] = rv;
        }
    }
}

// ---------------- launch ----------------
extern "C" void kernel_launch(void* const* d_in, const int* in_sizes, int n_in,
                              void* d_out, int out_size, void* d_ws, size_t ws_size,
                              hipStream_t stream) {
    const float* x        = (const float*)d_in[0];
    const float* mask0    = (const float*)d_in[1];
    const float* Wq       = (const float*)d_in[2];
    const float* Wk       = (const float*)d_in[3];
    const float* bk       = (const float*)d_in[4];
    const float* Wv       = (const float*)d_in[5];
    const float* bv       = (const float*)d_in[6];
    const float* Wo       = (const float*)d_in[7];
    const float* bo       = (const float*)d_in[8];
    const float* rwb      = (const float*)d_in[9];
    const float* rrb      = (const float*)d_in[10];
    const float* r_kernel = (const float*)d_in[11];
    const float* gamma    = (const float*)d_in[12];
    const float* beta     = (const float*)d_in[13];
    float* out = (float*)d_out;

    unsigned* QWt = (unsigned*)d_ws;                 // 196608 dwords
    unsigned* QRt = QWt + 196608;                    // 196608
    unsigned* KVM = QRt + 196608;                    // 1048576
    float4*   P   = (float4*)(KVM + 1048576);        // 524288 float4 (8 MB)
    unsigned short* phiB = (unsigned short*)(P + 524288);  // 262144 ushorts

    k_phi<<<256, 192, 0, stream>>>(r_kernel, phiB);
    k_qkv<<<256, 192, 0, stream>>>(x, Wq, Wk, bk, Wv, bv, rwb, rrb, mask0,
                                   QWt, QRt, KVM);
    k_attn<<<dim3(16, 16, 4), 256, 0, stream>>>(QWt, QRt, KVM, phiB, P);
    k_out<<<512, 256, 0, stream>>>(P, Wo, bo, x, gamma, beta, out);
}

// Round 5
// 153.942 us; speedup vs baseline: 1.6405x; 1.0146x over previous
//
#include <hip/hip_runtime.h>
#include <hip/hip_bf16.h>
#include <math.h>

#define LOG2E 1.4426950408889634f
#define IS6   0.4082482904638630f

typedef _Float16 h2 __attribute__((ext_vector_type(2)));

#if defined(__has_builtin)
#if __has_builtin(__builtin_amdgcn_fdot2)
#define FDOT2(a,b,c) __builtin_amdgcn_fdot2((a),(b),(c),false)
#endif
#endif
#ifndef FDOT2
#define FDOT2(a,b,c) ((float)(a).x*(float)(b).x + (float)(a).y*(float)(b).y + (c))
#endif

__device__ __forceinline__ unsigned packh2(float x, float y) {
    h2 v; v.x = (_Float16)x; v.y = (_Float16)y;
    return *(unsigned*)&v;
}
__device__ __forceinline__ h2 ash2(unsigned u) { return *(h2*)&u; }

// ---------------- kernel 1 (merged): QKV projections + phi table ----------------
// blocks [0,1024): qkv — 4 rows/block, 192 thr, thread = (row r, col-pair cp)
//   QWt/QRt: [bn][hp][s] f16x2, pre-scaled by 1/sqrt(6), log2e folded.
//   KVM row = 8 dwords (32B): [k01,k23,k45,mterm | v01,v23,v45,pad] (all f16x2 except mterm f32)
// blocks [1024,1280): phi — 8 t/block, 192 thr
//   phiB: [n][t][8] f16
__global__ __launch_bounds__(192)
void k_pre(const float* __restrict__ x,
           const float* __restrict__ Wq, const float* __restrict__ Wk,
           const float* __restrict__ bk, const float* __restrict__ Wv,
           const float* __restrict__ bv,
           const float* __restrict__ rwb, const float* __restrict__ rrb,
           const float* __restrict__ mask, const float* __restrict__ rk,
           unsigned* __restrict__ QWt, unsigned* __restrict__ QRt,
           unsigned* __restrict__ KVM, unsigned short* __restrict__ phiB) {
    __shared__ float rrowS[8 * 192];
    int tid = threadIdx.x;
    if (blockIdx.x < 1024) {
        // ---- QKV part ----
        int r = tid / 48, cp = tid - r * 48, c0 = cp * 2;
        int row = blockIdx.x * 4 + r;
        const float* xr = x + (size_t)row * 192;
        float qa = 0.f, qb = 0.f, ka = 0.f, kb = 0.f, va = 0.f, vb = 0.f;
        #pragma unroll 4
        for (int d = 0; d < 192; ++d) {
            float xd = xr[d];
            float2 wq = *(const float2*)&Wq[d * 96 + c0];
            float2 wk = *(const float2*)&Wk[d * 96 + c0];
            float2 wv = *(const float2*)&Wv[d * 96 + c0];
            qa += xd * wq.x; qb += xd * wq.y;
            ka += xd * wk.x; kb += xd * wk.y;
            va += xd * wv.x; vb += xd * wv.y;
        }
        int b = row >> 10, s = row & 1023;
        int n = c0 / 6, hp = (c0 - n * 6) >> 1;
        int bn = b * 16 + n;
        unsigned qwp = packh2((qa + rwb[c0]) * (IS6 * LOG2E), (qb + rwb[c0 + 1]) * (IS6 * LOG2E));
        unsigned qrp = packh2((qa + rrb[c0]) * (IS6 * LOG2E), (qb + rrb[c0 + 1]) * (IS6 * LOG2E));
        size_t qo = ((size_t)(bn * 3 + hp) << 10) + s;
        QWt[qo] = qwp;
        QRt[qo] = qrp;
        size_t ko = ((size_t)bn * 1024 + s) * 8;
        KVM[ko + hp]     = packh2(ka + bk[c0], kb + bk[c0 + 1]);
        KVM[ko + 4 + hp] = packh2(va + bv[c0], vb + bv[c0 + 1]);
        if (hp == 0) {
            float m = 1e6f * (mask[b * 1024 + s] - 1.0f) * LOG2E;
            KVM[ko + 3] = __float_as_uint(m);
            KVM[ko + 7] = 0;
        }
    } else {
        // ---- phi part ----
        int t0 = (blockIdx.x - 1024) * 8;
        {
            int d = tid;
            int dd = d < 96 ? d : d - 96;
            float w = exp2f(-(float)dd * 0.13841367062030676f);  // log2(10000)/96
            #pragma unroll
            for (int tl = 0; tl < 8; ++tl) {
                float ang = (float)(1024 - (t0 + tl)) * w;       // radians
                rrowS[tl * 192 + d] = (d < 96) ? __sinf(ang) : __cosf(ang);
            }
        }
        __syncthreads();
        int c = tid % 96, tg = tid / 96;
        float acc0 = 0.f, acc1 = 0.f, acc2 = 0.f, acc3 = 0.f;
        #pragma unroll 4
        for (int d = 0; d < 192; ++d) {
            float wk = rk[d * 96 + c];
            acc0 += rrowS[(tg * 4 + 0) * 192 + d] * wk;
            acc1 += rrowS[(tg * 4 + 1) * 192 + d] * wk;
            acc2 += rrowS[(tg * 4 + 2) * 192 + d] * wk;
            acc3 += rrowS[(tg * 4 + 3) * 192 + d] * wk;
        }
        int n = c / 6, h = c - n * 6;
        float av[4] = {acc0, acc1, acc2, acc3};
        #pragma unroll
        for (int k = 0; k < 4; ++k) {
            int t = t0 + tg * 4 + k;
            _Float16 v = (_Float16)av[k];
            phiB[(n * 2048 + t) * 8 + h] = *(unsigned short*)&v;
        }
        if (tg == 0 && c < 32) {
            int nn = c >> 1, hh = 6 + (c & 1);
            #pragma unroll
            for (int k = 0; k < 8; ++k) phiB[(nn * 2048 + t0 + k) * 8 + hh] = 0;
        }
    }
}

// ---------------- kernel 2: fused attention ----------------
// grid (16,16,4): bx = ic + 4*jc; block 128 thr; thread = queries i0+tid, i0+128+tid.
// f32 partials (denom, a0..a5) -> P[jc][bn][i][8]
__global__ __launch_bounds__(128)
void k_attn(const unsigned* __restrict__ QWt, const unsigned* __restrict__ QRt,
            const unsigned* __restrict__ KVM,
            const unsigned short* __restrict__ phiB,
            float4* __restrict__ P) {
    __shared__ uint4 phiS[511];     // 8176 B
    __shared__ uint4 kvS[512];      // 8192 B : 256 rows x 32B
    int tid = threadIdx.x;
    int ic = blockIdx.x & 3, jc = blockIdx.x >> 2;
    int n = blockIdx.y, b = blockIdx.z;
    int i0 = ic * 256, j0 = jc * 256;
    int bn = b * 16 + n;

    int tmin = 769 - i0 + j0;
    const uint4* phg = (const uint4*)phiB + (n * 2048 + tmin);
    for (int r = tid; r < 511; r += 128) phiS[r] = phg[r];
    const uint4* kvg = (const uint4*)KVM + ((size_t)bn * 1024 + j0) * 2;
    for (int r = tid; r < 512; r += 128) kvS[r] = kvg[r];
    __syncthreads();

    int iA = i0 + tid;
    size_t qbA = (size_t)bn * 3072 + iA;
    h2 qwA0 = ash2(QWt[qbA]), qwA1 = ash2(QWt[qbA + 1024]), qwA2 = ash2(QWt[qbA + 2048]);
    h2 qrA0 = ash2(QRt[qbA]), qrA1 = ash2(QRt[qbA + 1024]), qrA2 = ash2(QRt[qbA + 2048]);
    size_t qbB = qbA + 128;
    h2 qwB0 = ash2(QWt[qbB]), qwB1 = ash2(QWt[qbB + 1024]), qwB2 = ash2(QWt[qbB + 2048]);
    h2 qrB0 = ash2(QRt[qbB]), qrB1 = ash2(QRt[qbB + 1024]), qrB2 = ash2(QRt[qbB + 2048]);

    float dA = 0.f, aA0 = 0.f, aA1 = 0.f, aA2 = 0.f, aA3 = 0.f, aA4 = 0.f, aA5 = 0.f;
    float dB = 0.f, aB0 = 0.f, aB1 = 0.f, aB2 = 0.f, aB3 = 0.f, aB4 = 0.f, aB5 = 0.f;
    const uint4* phA = phiS + (255 - tid);
    const uint4* phB = phiS + (127 - tid);

    #pragma unroll 2
    for (int jj = 0; jj < 256; ++jj) {
        uint4 K = kvS[2 * jj];          // broadcast
        uint4 V = kvS[2 * jj + 1];      // broadcast
        uint4 pA = phA[jj];
        uint4 pB = phB[jj];
        float mterm = __uint_as_float(K.w);
        float scA = FDOT2(ash2(K.x), qwA0,
                    FDOT2(ash2(K.y), qwA1,
                    FDOT2(ash2(K.z), qwA2, mterm)));
        scA = FDOT2(ash2(pA.x), qrA0,
              FDOT2(ash2(pA.y), qrA1,
              FDOT2(ash2(pA.z), qrA2, scA)));
        float scB = FDOT2(ash2(K.x), qwB0,
                    FDOT2(ash2(K.y), qwB1,
                    FDOT2(ash2(K.z), qwB2, mterm)));
        scB = FDOT2(ash2(pB.x), qrB0,
              FDOT2(ash2(pB.y), qrB1,
              FDOT2(ash2(pB.z), qrB2, scB)));
        float eA = exp2f(scA), eB = exp2f(scB);
        dA += eA; dB += eB;
        h2 v0 = ash2(V.x), v1 = ash2(V.y), v2 = ash2(V.z);
        aA0 += eA * (float)v0.x; aA1 += eA * (float)v0.y;
        aA2 += eA * (float)v1.x; aA3 += eA * (float)v1.y;
        aA4 += eA * (float)v2.x; aA5 += eA * (float)v2.y;
        aB0 += eB * (float)v0.x; aB1 += eB * (float)v0.y;
        aB2 += eB * (float)v1.x; aB3 += eB * (float)v1.y;
        aB4 += eB * (float)v2.x; aB5 += eB * (float)v2.y;
    }
    size_t pb = ((((size_t)(jc * 64 + bn)) << 10) + iA) * 2;
    P[pb]     = make_float4(dA, aA0, aA1, aA2);
    P[pb + 1] = make_float4(aA3, aA4, aA5, 0.f);
    P[pb + 256] = make_float4(dB, aB0, aB1, aB2);
    P[pb + 257] = make_float4(aB3, aB4, aB5, 0.f);
}

// ---------------- kernel 3: combine + Wo projection + residual + LayerNorm ----------------
__global__ __launch_bounds__(256)
void k_out(const float4* __restrict__ P, const float* __restrict__ Wo,
           const float* __restrict__ bo, const float* __restrict__ x,
           const float* __restrict__ gamma, const float* __restrict__ beta,
           float* __restrict__ out) {
    __shared__ unsigned WoS[96 * 96];
    __shared__ float avS[8 * 96];
    int tid = threadIdx.x;
    int row0 = blockIdx.x * 8;
    for (int idx = tid; idx < 9216; idx += 256) {
        int c = idx / 96, pd = idx - c * 96;
        float2 w = *(const float2*)&Wo[c * 192 + pd * 2];
        WoS[idx] = packh2(w.x, w.y);
    }
    if (tid < 128) {
        int rl = tid >> 4, n = tid & 15;
        int row = row0 + rl, b = row >> 10, i = row & 1023;
        int bn = b * 16 + n;
        float d = 0.f, s0 = 0.f, s1 = 0.f, s2 = 0.f, s3 = 0.f, s4 = 0.f, s5 = 0.f;
        #pragma unroll
        for (int jjc = 0; jjc < 4; ++jjc) {
            size_t pb = ((((size_t)(jjc * 64 + bn)) << 10) + i) * 2;
            float4 u = P[pb], v = P[pb + 1];
            d += u.x; s0 += u.y; s1 += u.z; s2 += u.w;
            s3 += v.x; s4 += v.y; s5 += v.z;
        }
        float inv = 1.0f / d;
        float* o = &avS[rl * 96 + n * 6];
        o[0] = s0 * inv; o[1] = s1 * inv; o[2] = s2 * inv;
        o[3] = s3 * inv; o[4] = s4 * inv; o[5] = s5 * inv;
    }
    __syncthreads();

    int lane = tid & 63, wv = tid >> 6;
    bool act = lane < 48;
    int d0 = lane * 4;
    #pragma unroll
    for (int rr = 0; rr < 2; ++rr) {
        int r = wv * 2 + rr, row = row0 + r;
        float ax = 0.f, ay = 0.f, az = 0.f, aw = 0.f;
        if (act) {
            float4 bq = *(const float4*)&bo[d0];
            float4 xq = *(const float4*)&x[(size_t)row * 192 + d0];
            ax = bq.x + xq.x; ay = bq.y + xq.y; az = bq.z + xq.z; aw = bq.w + xq.w;
            for (int c2 = 0; c2 < 96; ++c2) {
                float a = avS[r * 96 + c2];
                uint2 wp = *(uint2*)&WoS[c2 * 96 + lane * 2];
                h2 w0 = ash2(wp.x), w1 = ash2(wp.y);
                ax += a * (float)w0.x; ay += a * (float)w0.y;
                az += a * (float)w1.x; aw += a * (float)w1.y;
            }
        }
        float sum = act ? (ax + ay + az + aw) : 0.f;
        #pragma unroll
        for (int off = 32; off; off >>= 1) sum += __shfl_xor(sum, off, 64);
        float mu = sum * (1.0f / 192.0f);
        float dx = ax - mu, dy = ay - mu, dz = az - mu, dw = aw - mu;
        float vs = act ? (dx * dx + dy * dy + dz * dz + dw * dw) : 0.f;
        #pragma unroll
        for (int off = 32; off; off >>= 1) vs += __shfl_xor(vs, off, 64);
        float rstd = rsqrtf(vs * (1.0f / 192.0f) + 1e-9f);
        if (act) {
            float4 g = *(const float4*)&gamma[d0];
            float4 bb = *(const float4*)&beta[d0];
            float4 rv;
            rv.x = dx * rstd * g.x + bb.x;
            rv.y = dy * rstd * g.y + bb.y;
            rv.z = dz * rstd * g.z + bb.z;
            rv.w = dw * rstd * g.w + bb.w;
            *(float4*)&out[(size_t)row * 192 + d0] = rv;
        }
    }
}

// ---------------- launch ----------------
extern "C" void kernel_launch(void* const* d_in, const int* in_sizes, int n_in,
                              void* d_out, int out_size, void* d_ws, size_t ws_size,
                              hipStream_t stream) {
    const float* x        = (const float*)d_in[0];
    const float* mask0    = (const float*)d_in[1];
    const float* Wq       = (const float*)d_in[2];
    const float* Wk       = (const float*)d_in[3];
    const float* bk       = (const float*)d_in[4];
    const float* Wv       = (const float*)d_in[5];
    const float* bv       = (const float*)d_in[6];
    const float* Wo       = (const float*)d_in[7];
    const float* bo       = (const float*)d_in[8];
    const float* rwb      = (const float*)d_in[9];
    const float* rrb      = (const float*)d_in[10];
    const float* r_kernel = (const float*)d_in[11];
    const float* gamma    = (const float*)d_in[12];
    const float* beta     = (const float*)d_in[13];
    float* out = (float*)d_out;

    unsigned* QWt = (unsigned*)d_ws;                 // 196608 dwords
    unsigned* QRt = QWt + 196608;                    // 196608 dwords
    unsigned* KVM = QRt + 196608;                    // 524288 dwords (32B/row)
    float4*   P   = (float4*)(KVM + 524288);         // 524288 float4 (8 MB)
    unsigned short* phiB = (unsigned short*)(P + 524288);  // 262144 ushorts

    k_pre<<<1280, 192, 0, stream>>>(x, Wq, Wk, bk, Wv, bv, rwb, rrb, mask0,
                                    r_kernel, QWt, QRt, KVM, phiB);
    k_attn<<<dim3(16, 16, 4), 128, 0, stream>>>(QWt, QRt, KVM, phiB, P);
    k_out<<<512, 256, 0, stream>>>(P, Wo, bo, x, gamma, beta, out);
}

// Round 6
// 118.751 us; speedup vs baseline: 2.1267x; 1.2963x over previous
//
#include <hip/hip_runtime.h>
#include <hip/hip_bf16.h>
#include <math.h>

#define LOG2E 1.4426950408889634f
#define IS6   0.4082482904638630f

typedef _Float16 h2 __attribute__((ext_vector_type(2)));

#if defined(__has_builtin)
#if __has_builtin(__builtin_amdgcn_fdot2)
#define FDOT2(a,b,c) __builtin_amdgcn_fdot2((a),(b),(c),false)
#endif
#endif
#ifndef FDOT2
#define FDOT2(a,b,c) ((float)(a).x*(float)(b).x + (float)(a).y*(float)(b).y + (c))
#endif

__device__ __forceinline__ unsigned packh2(float x, float y) {
    h2 v; v.x = (_Float16)x; v.y = (_Float16)y;
    return *(unsigned*)&v;
}
__device__ __forceinline__ h2 ash2(unsigned u) { return *(h2*)&u; }

// ---------------- kernel 1 (merged): QKV projections + phi table ----------------
// blocks [0,256): qkv — 16 rows/block, 192 thr, 2 rows/thread, float4 W loads.
//   QWt/QRt: [bn][hp][s] f16x2, scaled by 1/sqrt(6)*log2e, biases folded.
//   KVM row = 8 dwords (32B): [k01,k23,k45,mterm | v01,v23,v45,0]
// blocks [256,512): phi — 8 t/block; phiB: [n][t][8] f16
__global__ __launch_bounds__(192)
void k_pre(const float* __restrict__ x,
           const float* __restrict__ Wq, const float* __restrict__ Wk,
           const float* __restrict__ bk, const float* __restrict__ Wv,
           const float* __restrict__ bv,
           const float* __restrict__ rwb, const float* __restrict__ rrb,
           const float* __restrict__ mask, const float* __restrict__ rk,
           unsigned* __restrict__ QWt, unsigned* __restrict__ QRt,
           unsigned* __restrict__ KVM, unsigned short* __restrict__ phiB) {
    __shared__ float xs[16 * 194];
    __shared__ float rrowS[8 * 192];
    int tid = threadIdx.x;
    if (blockIdx.x < 256) {
        // ---- QKV ----
        int row0 = blockIdx.x * 16;
        for (int idx = tid; idx < 16 * 192; idx += 192) {
            int r = idx / 192, cc = idx - r * 192;
            xs[r * 194 + cc] = x[(size_t)(row0 + r) * 192 + cc];
        }
        __syncthreads();
        int ct = tid % 24, rg = tid / 24, c0 = ct * 4;
        float aq[2][4] = {{0,0,0,0},{0,0,0,0}};
        float ak[2][4] = {{0,0,0,0},{0,0,0,0}};
        float av[2][4] = {{0,0,0,0},{0,0,0,0}};
        const float* x0 = &xs[(rg * 2 + 0) * 194];
        const float* x1 = &xs[(rg * 2 + 1) * 194];
        #pragma unroll 2
        for (int d = 0; d < 192; ++d) {
            float4 wq = *(const float4*)&Wq[d * 96 + c0];
            float4 wk = *(const float4*)&Wk[d * 96 + c0];
            float4 wv = *(const float4*)&Wv[d * 96 + c0];
            float xa = x0[d], xb = x1[d];
            aq[0][0] += xa * wq.x; aq[0][1] += xa * wq.y; aq[0][2] += xa * wq.z; aq[0][3] += xa * wq.w;
            ak[0][0] += xa * wk.x; ak[0][1] += xa * wk.y; ak[0][2] += xa * wk.z; ak[0][3] += xa * wk.w;
            av[0][0] += xa * wv.x; av[0][1] += xa * wv.y; av[0][2] += xa * wv.z; av[0][3] += xa * wv.w;
            aq[1][0] += xb * wq.x; aq[1][1] += xb * wq.y; aq[1][2] += xb * wq.z; aq[1][3] += xb * wq.w;
            ak[1][0] += xb * wk.x; ak[1][1] += xb * wk.y; ak[1][2] += xb * wk.z; ak[1][3] += xb * wk.w;
            av[1][0] += xb * wv.x; av[1][1] += xb * wv.y; av[1][2] += xb * wv.z; av[1][3] += xb * wv.w;
        }
        #pragma unroll
        for (int rr = 0; rr < 2; ++rr) {
            int row = row0 + rg * 2 + rr;
            int b = row >> 10, s = row & 1023;
            #pragma unroll
            for (int pp = 0; pp < 2; ++pp) {
                int pg = 2 * ct + pp;               // pair index 0..47
                int n = pg / 3, hp = pg - n * 3;
                int cA = c0 + 2 * pp;
                int bn = b * 16 + n;
                unsigned qwp = packh2((aq[rr][2*pp]   + rwb[cA])     * (IS6 * LOG2E),
                                      (aq[rr][2*pp+1] + rwb[cA + 1]) * (IS6 * LOG2E));
                unsigned qrp = packh2((aq[rr][2*pp]   + rrb[cA])     * (IS6 * LOG2E),
                                      (aq[rr][2*pp+1] + rrb[cA + 1]) * (IS6 * LOG2E));
                size_t qo = ((size_t)(bn * 3 + hp) << 10) + s;
                QWt[qo] = qwp;
                QRt[qo] = qrp;
                size_t ko = ((size_t)bn * 1024 + s) * 8;
                KVM[ko + hp]     = packh2(ak[rr][2*pp] + bk[cA], ak[rr][2*pp+1] + bk[cA+1]);
                KVM[ko + 4 + hp] = packh2(av[rr][2*pp] + bv[cA], av[rr][2*pp+1] + bv[cA+1]);
                if (hp == 0) {
                    float m = 1e6f * (mask[b * 1024 + s] - 1.0f) * LOG2E;
                    KVM[ko + 3] = __float_as_uint(m);
                    KVM[ko + 7] = 0;
                }
            }
        }
    } else {
        // ---- phi ----
        int t0 = (blockIdx.x - 256) * 8;
        {
            int d = tid;
            int dd = d < 96 ? d : d - 96;
            float w = exp2f(-(float)dd * 0.13841367062030676f);  // log2(10000)/96
            #pragma unroll
            for (int tl = 0; tl < 8; ++tl) {
                float ang = (float)(1024 - (t0 + tl)) * w;
                rrowS[tl * 192 + d] = (d < 96) ? __sinf(ang) : __cosf(ang);
            }
        }
        __syncthreads();
        int c = tid % 96, tg = tid / 96;
        float acc0 = 0.f, acc1 = 0.f, acc2 = 0.f, acc3 = 0.f;
        #pragma unroll 4
        for (int d = 0; d < 192; ++d) {
            float wk = rk[d * 96 + c];
            acc0 += rrowS[(tg * 4 + 0) * 192 + d] * wk;
            acc1 += rrowS[(tg * 4 + 1) * 192 + d] * wk;
            acc2 += rrowS[(tg * 4 + 2) * 192 + d] * wk;
            acc3 += rrowS[(tg * 4 + 3) * 192 + d] * wk;
        }
        int n = c / 6, h = c - n * 6;
        float avv[4] = {acc0, acc1, acc2, acc3};
        #pragma unroll
        for (int k = 0; k < 4; ++k) {
            int t = t0 + tg * 4 + k;
            _Float16 v = (_Float16)avv[k];
            phiB[(n * 2048 + t) * 8 + h] = *(unsigned short*)&v;
        }
        if (tg == 0 && c < 32) {
            int nn = c >> 1, hh = 6 + (c & 1);
            #pragma unroll
            for (int k = 0; k < 8; ++k) phiB[(nn * 2048 + t0 + k) * 8 + hh] = 0;
        }
    }
}

// ---------------- kernel 2: fused attention ----------------
// grid (8,16,4): jc,n,b; block 512 thr (8 waves); queries i = tid, tid+512; 128 j/block.
// Partials packed f16 per query: [d,a0|a1,a2|a3,a4|a5,0] -> P[jc][bn][i]
__global__ __launch_bounds__(512, 4)
void k_attn(const unsigned* __restrict__ QWt, const unsigned* __restrict__ QRt,
            const unsigned* __restrict__ KVM,
            const unsigned short* __restrict__ phiB,
            uint4* __restrict__ P) {
    __shared__ uint4 phiS[1151];    // 18416 B
    __shared__ uint4 kvS[256];      // 4096 B : 128 rows x 32B
    int tid = threadIdx.x;
    int jc = blockIdx.x, n = blockIdx.y, b = blockIdx.z;
    int j0 = jc * 128;
    int bn = b * 16 + n;

    const uint4* phg = (const uint4*)phiB + (n * 2048 + j0 + 1);
    for (int r = tid; r < 1151; r += 512) phiS[r] = phg[r];
    const uint4* kvg = (const uint4*)KVM + ((size_t)bn * 1024 + j0) * 2;
    if (tid < 256) kvS[tid] = kvg[tid];
    __syncthreads();

    int iA = tid, iB = tid + 512;
    size_t qbA = (size_t)bn * 3072 + iA;
    h2 qwA0 = ash2(QWt[qbA]), qwA1 = ash2(QWt[qbA + 1024]), qwA2 = ash2(QWt[qbA + 2048]);
    h2 qrA0 = ash2(QRt[qbA]), qrA1 = ash2(QRt[qbA + 1024]), qrA2 = ash2(QRt[qbA + 2048]);
    size_t qbB = qbA + 512;
    h2 qwB0 = ash2(QWt[qbB]), qwB1 = ash2(QWt[qbB + 1024]), qwB2 = ash2(QWt[qbB + 2048]);
    h2 qrB0 = ash2(QRt[qbB]), qrB1 = ash2(QRt[qbB + 1024]), qrB2 = ash2(QRt[qbB + 2048]);

    float dA = 0.f, aA0 = 0.f, aA1 = 0.f, aA2 = 0.f, aA3 = 0.f, aA4 = 0.f, aA5 = 0.f;
    float dB = 0.f, aB0 = 0.f, aB1 = 0.f, aB2 = 0.f, aB3 = 0.f, aB4 = 0.f, aB5 = 0.f;
    const uint4* phA = phiS + (1023 - iA);   // idx = 1023 - i + jj
    const uint4* phB = phiS + (1023 - iB);

    #pragma unroll 2
    for (int jj = 0; jj < 128; ++jj) {
        uint4 K = kvS[2 * jj];          // broadcast
        uint4 V = kvS[2 * jj + 1];      // broadcast
        uint4 pA = phA[jj];
        uint4 pB = phB[jj];
        float mterm = __uint_as_float(K.w);
        float scA = FDOT2(ash2(K.x), qwA0,
                    FDOT2(ash2(K.y), qwA1,
                    FDOT2(ash2(K.z), qwA2, mterm)));
        scA = FDOT2(ash2(pA.x), qrA0,
              FDOT2(ash2(pA.y), qrA1,
              FDOT2(ash2(pA.z), qrA2, scA)));
        float scB = FDOT2(ash2(K.x), qwB0,
                    FDOT2(ash2(K.y), qwB1,
                    FDOT2(ash2(K.z), qwB2, mterm)));
        scB = FDOT2(ash2(pB.x), qrB0,
              FDOT2(ash2(pB.y), qrB1,
              FDOT2(ash2(pB.z), qrB2, scB)));
        float eA = exp2f(scA), eB = exp2f(scB);
        dA += eA; dB += eB;
        h2 v0 = ash2(V.x), v1 = ash2(V.y), v2 = ash2(V.z);
        aA0 += eA * (float)v0.x; aA1 += eA * (float)v0.y;
        aA2 += eA * (float)v1.x; aA3 += eA * (float)v1.y;
        aA4 += eA * (float)v2.x; aA5 += eA * (float)v2.y;
        aB0 += eB * (float)v0.x; aB1 += eB * (float)v0.y;
        aB2 += eB * (float)v1.x; aB3 += eB * (float)v1.y;
        aB4 += eB * (float)v2.x; aB5 += eB * (float)v2.y;
    }
    size_t pb = ((size_t)(jc * 64 + bn)) << 10;
    uint4 sA, sB;
    sA.x = packh2(dA, aA0); sA.y = packh2(aA1, aA2);
    sA.z = packh2(aA3, aA4); sA.w = packh2(aA5, 0.f);
    sB.x = packh2(dB, aB0); sB.y = packh2(aB1, aB2);
    sB.z = packh2(aB3, aB4); sB.w = packh2(aB5, 0.f);
    P[pb + iA] = sA;
    P[pb + iB] = sB;
}

// ---------------- kernel 3: combine + Wo projection + residual + LayerNorm ----------------
// 256 blocks x 256 thr, 16 rows/block; Wo staged once per block as f16.
__global__ __launch_bounds__(256)
void k_out(const uint4* __restrict__ P, const float* __restrict__ Wo,
           const float* __restrict__ bo, const float* __restrict__ x,
           const float* __restrict__ gamma, const float* __restrict__ beta,
           float* __restrict__ out) {
    __shared__ unsigned WoS[96 * 96];   // 36864 B
    __shared__ float avS[16 * 96];      // 6144 B
    int tid = threadIdx.x;
    int row0 = blockIdx.x * 16;
    for (int idx = tid; idx < 9216; idx += 256) {
        int c = idx / 96, pd = idx - c * 96;
        float2 w = *(const float2*)&Wo[c * 192 + pd * 2];
        WoS[idx] = packh2(w.x, w.y);
    }
    {   // combine 8 j-chunks; thread = (head n, local row rl); coalesced P reads
        int n = tid >> 4, rl = tid & 15;
        int row = row0 + rl, b = row >> 10, i = row & 1023;
        int bn = b * 16 + n;
        float d = 0.f, s0 = 0.f, s1 = 0.f, s2 = 0.f, s3 = 0.f, s4 = 0.f, s5 = 0.f;
        #pragma unroll
        for (int jjc = 0; jjc < 8; ++jjc) {
            uint4 u = P[(((size_t)(jjc * 64 + bn)) << 10) + i];
            h2 x0 = ash2(u.x), x1 = ash2(u.y), x2 = ash2(u.z), x3 = ash2(u.w);
            d  += (float)x0.x; s0 += (float)x0.y; s1 += (float)x1.x; s2 += (float)x1.y;
            s3 += (float)x2.x; s4 += (float)x2.y; s5 += (float)x3.x;
        }
        float inv = 1.0f / d;
        float* o = &avS[rl * 96 + n * 6];
        o[0] = s0 * inv; o[1] = s1 * inv; o[2] = s2 * inv;
        o[3] = s3 * inv; o[4] = s4 * inv; o[5] = s5 * inv;
    }
    __syncthreads();

    int lane = tid & 63, wv = tid >> 6;
    bool act = lane < 48;
    int d0 = lane * 4;
    #pragma unroll
    for (int rr = 0; rr < 4; ++rr) {
        int r = wv * 4 + rr, row = row0 + r;
        float ax = 0.f, ay = 0.f, az = 0.f, aw = 0.f;
        if (act) {
            float4 bq = *(const float4*)&bo[d0];
            float4 xq = *(const float4*)&x[(size_t)row * 192 + d0];
            ax = bq.x + xq.x; ay = bq.y + xq.y; az = bq.z + xq.z; aw = bq.w + xq.w;
            for (int c2 = 0; c2 < 96; ++c2) {
                float a = avS[r * 96 + c2];
                uint2 wp = *(uint2*)&WoS[c2 * 96 + lane * 2];
                h2 w0 = ash2(wp.x), w1 = ash2(wp.y);
                ax += a * (float)w0.x; ay += a * (float)w0.y;
                az += a * (float)w1.x; aw += a * (float)w1.y;
            }
        }
        float sum = act ? (ax + ay + az + aw) : 0.f;
        #pragma unroll
        for (int off = 32; off; off >>= 1) sum += __shfl_xor(sum, off, 64);
        float mu = sum * (1.0f / 192.0f);
        float dx = ax - mu, dy = ay - mu, dz = az - mu, dw = aw - mu;
        float vs = act ? (dx * dx + dy * dy + dz * dz + dw * dw) : 0.f;
        #pragma unroll
        for (int off = 32; off; off >>= 1) vs += __shfl_xor(vs, off, 64);
        float rstd = rsqrtf(vs * (1.0f / 192.0f) + 1e-9f);
        if (act) {
            float4 g = *(const float4*)&gamma[d0];
            float4 bb = *(const float4*)&beta[d0];
            float4 rv;
            rv.x = dx * rstd * g.x + bb.x;
            rv.y = dy * rstd * g.y + bb.y;
            rv.z = dz * rstd * g.z + bb.z;
            rv.w = dw * rstd * g.w + bb.w;
            *(float4*)&out[(size_t)row * 192 + d0] = rv;
        }
    }
}

// ---------------- launch ----------------
extern "C" void kernel_launch(void* const* d_in, const int* in_sizes, int n_in,
                              void* d_out, int out_size, void* d_ws, size_t ws_size,
                              hipStream_t stream) {
    const float* x        = (const float*)d_in[0];
    const float* mask0    = (const float*)d_in[1];
    const float* Wq       = (const float*)d_in[2];
    const float* Wk       = (const float*)d_in[3];
    const float* bk       = (const float*)d_in[4];
    const float* Wv       = (const float*)d_in[5];
    const float* bv       = (const float*)d_in[6];
    const float* Wo       = (const float*)d_in[7];
    const float* bo       = (const float*)d_in[8];
    const float* rwb      = (const float*)d_in[9];
    const float* rrb      = (const float*)d_in[10];
    const float* r_kernel = (const float*)d_in[11];
    const float* gamma    = (const float*)d_in[12];
    const float* beta     = (const float*)d_in[13];
    float* out = (float*)d_out;

    unsigned* QWt = (unsigned*)d_ws;                 // 196608 dwords
    unsigned* QRt = QWt + 196608;                    // 196608 dwords
    unsigned* KVM = QRt + 196608;                    // 524288 dwords (32B/row)
    uint4*    P   = (uint4*)(KVM + 524288);          // 524288 uint4 (8 MB)
    unsigned short* phiB = (unsigned short*)(P + 524288);  // 262144 ushorts

    k_pre<<<512, 192, 0, stream>>>(x, Wq, Wk, bk, Wv, bv, rwb, rrb, mask0,
                                   r_kernel, QWt, QRt, KVM, phiB);
    k_attn<<<dim3(8, 16, 4), 512, 0, stream>>>(QWt, QRt, KVM, phiB, P);
    k_out<<<256, 256, 0, stream>>>(P, Wo, bo, x, gamma, beta, out);
}

// Round 7
// 94.564 us; speedup vs baseline: 2.6706x; 1.2558x over previous
//
#include <hip/hip_runtime.h>
#include <hip/hip_bf16.h>
#include <math.h>

#define LOG2E 1.4426950408889634f
#define IS6   0.4082482904638630f

typedef _Float16 h2 __attribute__((ext_vector_type(2)));

#if defined(__has_builtin)
#if __has_builtin(__builtin_amdgcn_fdot2)
#define FDOT2(a,b,c) __builtin_amdgcn_fdot2((a),(b),(c),false)
#endif
#if __has_builtin(__builtin_amdgcn_exp2f)
#define EXP2(x) __builtin_amdgcn_exp2f(x)
#endif
#endif
#ifndef FDOT2
#define FDOT2(a,b,c) ((float)(a).x*(float)(b).x + (float)(a).y*(float)(b).y + (c))
#endif
#ifndef EXP2
#define EXP2(x) exp2f(x)
#endif

__device__ __forceinline__ unsigned packh2(float x, float y) {
    h2 v; v.x = (_Float16)x; v.y = (_Float16)y;
    return *(unsigned*)&v;
}
__device__ __forceinline__ h2 ash2(unsigned u) { return *(h2*)&u; }

// ---------------- kernel 0: pack W (f32 col-major) -> Whp[mat][col][dpair] f16x2 ----------------
__global__ __launch_bounds__(96)
void k_wpack(const float* __restrict__ Wq, const float* __restrict__ Wk,
             const float* __restrict__ Wv, unsigned* __restrict__ Whp) {
    int bid = blockIdx.x;                   // mat*96 + dp
    int mat = bid / 96, dp = bid - mat * 96;
    const float* W = mat == 0 ? Wq : (mat == 1 ? Wk : Wv);
    int c = threadIdx.x;                    // 0..95
    float w0 = W[(2 * dp) * 96 + c];
    float w1 = W[(2 * dp + 1) * 96 + c];
    Whp[(mat * 96 + c) * 96 + dp] = packh2(w0, w1);
}

// ---------------- kernel 1: QKV (transposed stores, SoA planes) + phi table ----------------
// qkv blocks [0,1152): rt = bid/18 (64-row tile), qb = bid%18; thread = (quad = tid>>6, s = tid&63)
//   QWt/QRt[3 hp][64 bn][1024 s] f16x2 (scaled IS6*LOG2E, biases folded)
//   Kpl/Vpl[3 hp][64 bn][1024 s] f16x2 (biases folded)
// phi blocks [1152,1664): 4 t/block; phiB[n][t][8] f16
__global__ __launch_bounds__(256)
void k_pre(const float* __restrict__ x, const unsigned* __restrict__ Whp,
           const float* __restrict__ bk, const float* __restrict__ bv,
           const float* __restrict__ rwb, const float* __restrict__ rrb,
           const float* __restrict__ rk,
           unsigned* __restrict__ QWt, unsigned* __restrict__ QRt,
           unsigned* __restrict__ Kpl, unsigned* __restrict__ Vpl,
           unsigned short* __restrict__ phiB) {
    __shared__ unsigned xs[64 * 97];        // 64 rows x 96 f16-pairs, pad 97
    __shared__ float rrowS[4 * 192];
    int tid = threadIdx.x;
    if (blockIdx.x < 1152) {
        int rt = blockIdx.x / 18, qb = blockIdx.x - rt * 18;
        int row0 = rt * 64;
        for (int idx = tid; idx < 6144; idx += 256) {
            int r = idx / 96, dpp = idx - r * 96;
            float2 xv = *(const float2*)&x[(size_t)(row0 + r) * 192 + dpp * 2];
            xs[r * 97 + dpp] = packh2(xv.x, xv.y);
        }
        __syncthreads();
        int quad = __builtin_amdgcn_readfirstlane(tid >> 6);
        int sl = tid & 63;
        int cq = qb * 4 + quad;             // 0..71
        int c0 = cq * 4;                    // 0..284
        int mat = c0 / 96, col0 = c0 - mat * 96;
        const unsigned* wb0 = Whp + (mat * 96 + col0) * 96;
        const unsigned* wb1 = wb0 + 96;
        const unsigned* wb2 = wb0 + 192;
        const unsigned* wb3 = wb0 + 288;
        const unsigned* xr = xs + sl * 97;
        float a0 = 0.f, a1 = 0.f, a2 = 0.f, a3 = 0.f;
        #pragma unroll 8
        for (int dp = 0; dp < 96; ++dp) {
            h2 xp = ash2(xr[dp]);
            a0 = FDOT2(xp, ash2(wb0[dp]), a0);
            a1 = FDOT2(xp, ash2(wb1[dp]), a1);
            a2 = FDOT2(xp, ash2(wb2[dp]), a2);
            a3 = FDOT2(xp, ash2(wb3[dp]), a3);
        }
        float av[4] = {a0, a1, a2, a3};
        int row = row0 + sl, b = row >> 10, s = row & 1023;
        if (mat == 0) {
            #pragma unroll
            for (int pp = 0; pp < 2; ++pp) {
                int cA = col0 + 2 * pp;
                int pg = cA >> 1;
                int nn = pg / 3, hp = pg - nn * 3;
                int bnn = b * 16 + nn;
                unsigned qw = packh2((av[2*pp]   + rwb[cA])   * (IS6 * LOG2E),
                                     (av[2*pp+1] + rwb[cA+1]) * (IS6 * LOG2E));
                unsigned qr = packh2((av[2*pp]   + rrb[cA])   * (IS6 * LOG2E),
                                     (av[2*pp+1] + rrb[cA+1]) * (IS6 * LOG2E));
                size_t qo = ((size_t)(hp * 64 + bnn) << 10) + s;
                QWt[qo] = qw;
                QRt[qo] = qr;
            }
        } else if (mat == 1) {
            #pragma unroll
            for (int pp = 0; pp < 2; ++pp) {
                int cA = col0 + 2 * pp;
                int pg = cA >> 1;
                int nn = pg / 3, hp = pg - nn * 3;
                int bnn = b * 16 + nn;
                Kpl[((size_t)(hp * 64 + bnn) << 10) + s] =
                    packh2(av[2*pp] + bk[cA], av[2*pp+1] + bk[cA+1]);
            }
        } else {
            #pragma unroll
            for (int pp = 0; pp < 2; ++pp) {
                int cA = col0 + 2 * pp;
                int pg = cA >> 1;
                int nn = pg / 3, hp = pg - nn * 3;
                int bnn = b * 16 + nn;
                Vpl[((size_t)(hp * 64 + bnn) << 10) + s] =
                    packh2(av[2*pp] + bv[cA], av[2*pp+1] + bv[cA+1]);
            }
        }
    } else {
        // ---- phi: 4 t per block ----
        int t0 = (blockIdx.x - 1152) * 4;
        for (int idx = tid; idx < 768; idx += 256) {
            int tl = idx / 192, d = idx - tl * 192;
            int dd = d < 96 ? d : d - 96;
            float w = exp2f(-(float)dd * 0.13841367062030676f);  // log2(10000)/96
            float ang = (float)(1024 - (t0 + tl)) * w;
            rrowS[idx] = (d < 96) ? __sinf(ang) : __cosf(ang);
        }
        __syncthreads();
        if (tid < 192) {
            int c = tid % 96, tg = tid / 96;     // tg 0..1, 2 t's each
            float acc0 = 0.f, acc1 = 0.f;
            #pragma unroll 4
            for (int d = 0; d < 192; ++d) {
                float wv = rk[d * 96 + c];
                acc0 += rrowS[(tg * 2 + 0) * 192 + d] * wv;
                acc1 += rrowS[(tg * 2 + 1) * 192 + d] * wv;
            }
            int n = c / 6, h = c - n * 6;
            _Float16 v0 = (_Float16)acc0, v1 = (_Float16)acc1;
            phiB[(n * 2048 + t0 + tg * 2 + 0) * 8 + h] = *(unsigned short*)&v0;
            phiB[(n * 2048 + t0 + tg * 2 + 1) * 8 + h] = *(unsigned short*)&v1;
            if (tg == 0 && c < 32) {
                int nn = c >> 1, hh = 6 + (c & 1);
                #pragma unroll
                for (int k = 0; k < 4; ++k)
                    phiB[(nn * 2048 + t0 + k) * 8 + hh] = 0;
            }
        }
    }
}

// ---------------- kernel 2: fused attention ----------------
// grid (16 jc, 16 n, 4 b) x 256 thr; thread = 4 ADJACENT queries i = 4*tid .. 4*tid+3.
// phi register chain: row(q+1, jj) == row(q, jj-1)  ->  1 phi read/iter for 4 queries.
// phiS XOR-swizzled (r ^ ((r>>3)&7)) to kill the stride-4-row bank conflict.
#define SWZ(r) ((r) ^ (((r) >> 3) & 7))
__global__ __launch_bounds__(256, 4)
void k_attn(const unsigned* __restrict__ QWt, const unsigned* __restrict__ QRt,
            const unsigned* __restrict__ Kpl, const unsigned* __restrict__ Vpl,
            const float* __restrict__ mask0,
            const unsigned short* __restrict__ phiB,
            uint4* __restrict__ P) {
    __shared__ uint4 phiS[1088];    // 17408 B
    __shared__ uint4 kS[64];        // {k01,k23,k45,mterm}
    __shared__ uint4 vS[64];        // {v01,v23,v45,0}
    int tid = threadIdx.x;
    int jc = blockIdx.x, n = blockIdx.y, b = blockIdx.z;
    int j0 = jc * 64;
    int bn = b * 16 + n;

    const uint4* phg = (const uint4*)phiB + (n * 2048 + j0 + 1);
    for (int r = tid; r < 1087; r += 256) phiS[SWZ(r)] = phg[r];
    if (tid < 64) {
        int j = j0 + tid;
        size_t base = ((size_t)bn << 10) + j;
        unsigned k01 = Kpl[base], k23 = Kpl[base + 65536], k45 = Kpl[base + 131072];
        unsigned v01 = Vpl[base], v23 = Vpl[base + 65536], v45 = Vpl[base + 131072];
        float mt = 1e6f * (mask0[b * 1024 + j] - 1.0f) * LOG2E;
        kS[tid] = make_uint4(k01, k23, k45, __float_as_uint(mt));
        vS[tid] = make_uint4(v01, v23, v45, 0u);
    }
    __syncthreads();

    int iA = tid * 4;
    size_t qb = ((size_t)bn) << 10;          // within plane; planes stride 65536
    h2 qw[4][3], qr[4][3];
    #pragma unroll
    for (int q = 0; q < 4; ++q) {
        #pragma unroll
        for (int hp = 0; hp < 3; ++hp) {
            qw[q][hp] = ash2(QWt[(size_t)hp * 65536 + qb + iA + q]);
            qr[q][hp] = ash2(QRt[(size_t)hp * 65536 + qb + iA + q]);
        }
    }
    float den[4] = {0.f, 0.f, 0.f, 0.f};
    float ac[4][6] = {};
    int Cb = 1023 - iA;
    uint4 r1 = phiS[SWZ(Cb - 1)];
    uint4 r2 = phiS[SWZ(Cb - 2)];
    uint4 r3 = phiS[SWZ(Cb - 3)];

    #pragma unroll 4
    for (int jj = 0; jj < 64; ++jj) {
        uint4 K = kS[jj];
        uint4 V = vS[jj];
        uint4 r0 = phiS[SWZ(Cb + jj)];
        float mt = __uint_as_float(K.w);
        uint4 ph[4] = {r0, r1, r2, r3};
        h2 v01 = ash2(V.x), v23 = ash2(V.y), v45 = ash2(V.z);
        #pragma unroll
        for (int q = 0; q < 4; ++q) {
            float sc = FDOT2(ash2(K.x), qw[q][0],
                       FDOT2(ash2(K.y), qw[q][1],
                       FDOT2(ash2(K.z), qw[q][2], mt)));
            sc = FDOT2(ash2(ph[q].x), qr[q][0],
                 FDOT2(ash2(ph[q].y), qr[q][1],
                 FDOT2(ash2(ph[q].z), qr[q][2], sc)));
            float e = EXP2(sc);
            den[q] += e;
            ac[q][0] += e * (float)v01.x; ac[q][1] += e * (float)v01.y;
            ac[q][2] += e * (float)v23.x; ac[q][3] += e * (float)v23.y;
            ac[q][4] += e * (float)v45.x; ac[q][5] += e * (float)v45.y;
        }
        r3 = r2; r2 = r1; r1 = r0;
    }
    size_t pb = ((size_t)(jc * 64 + bn)) << 10;   // chunk layout: [4 q][256 t]
    #pragma unroll
    for (int q = 0; q < 4; ++q) {
        uint4 st;
        st.x = packh2(den[q], ac[q][0]);
        st.y = packh2(ac[q][1], ac[q][2]);
        st.z = packh2(ac[q][3], ac[q][4]);
        st.w = packh2(ac[q][5], 0.f);
        P[pb + q * 256 + tid] = st;
    }
}

// ---------------- kernel 3: combine 16 chunks + Wo proj + residual + LayerNorm ----------------
__global__ __launch_bounds__(256)
void k_out(const uint4* __restrict__ P, const float* __restrict__ Wo,
           const float* __restrict__ bo, const float* __restrict__ x,
           const float* __restrict__ gamma, const float* __restrict__ beta,
           float* __restrict__ out) {
    __shared__ unsigned WoS[96 * 96];
    __shared__ float avS[16 * 96];
    int tid = threadIdx.x;
    int row0 = blockIdx.x * 16;
    for (int idx = tid; idx < 9216; idx += 256) {
        int c = idx / 96, pd = idx - c * 96;
        float2 w = *(const float2*)&Wo[c * 192 + pd * 2];
        WoS[idx] = packh2(w.x, w.y);
    }
    {   // combine: thread = (head n = tid>>4, local row rl = tid&15)
        int n = tid >> 4, rl = tid & 15;
        int row = row0 + rl, b = row >> 10, i = row & 1023;
        int bn = b * 16 + n;
        int q = i & 3, tt = i >> 2;
        float d = 0.f, s0 = 0.f, s1 = 0.f, s2 = 0.f, s3 = 0.f, s4 = 0.f, s5 = 0.f;
        #pragma unroll
        for (int jjc = 0; jjc < 16; ++jjc) {
            uint4 u = P[(((size_t)(jjc * 64 + bn)) << 10) + q * 256 + tt];
            h2 x0 = ash2(u.x), x1 = ash2(u.y), x2 = ash2(u.z), x3 = ash2(u.w);
            d  += (float)x0.x; s0 += (float)x0.y; s1 += (float)x1.x; s2 += (float)x1.y;
            s3 += (float)x2.x; s4 += (float)x2.y; s5 += (float)x3.x;
        }
        float inv = 1.0f / d;
        float* o = &avS[rl * 96 + n * 6];
        o[0] = s0 * inv; o[1] = s1 * inv; o[2] = s2 * inv;
        o[3] = s3 * inv; o[4] = s4 * inv; o[5] = s5 * inv;
    }
    __syncthreads();

    int lane = tid & 63, wv = tid >> 6;
    bool act = lane < 48;
    int d0 = lane * 4;
    #pragma unroll
    for (int rr = 0; rr < 4; ++rr) {
        int r = wv * 4 + rr, row = row0 + r;
        float ax = 0.f, ay = 0.f, az = 0.f, aw = 0.f;
        if (act) {
            float4 bq = *(const float4*)&bo[d0];
            float4 xq = *(const float4*)&x[(size_t)row * 192 + d0];
            ax = bq.x + xq.x; ay = bq.y + xq.y; az = bq.z + xq.z; aw = bq.w + xq.w;
            for (int c2 = 0; c2 < 96; ++c2) {
                float a = avS[r * 96 + c2];
                uint2 wp = *(uint2*)&WoS[c2 * 96 + lane * 2];
                h2 w0 = ash2(wp.x), w1 = ash2(wp.y);
                ax += a * (float)w0.x; ay += a * (float)w0.y;
                az += a * (float)w1.x; aw += a * (float)w1.y;
            }
        }
        float sum = act ? (ax + ay + az + aw) : 0.f;
        #pragma unroll
        for (int off = 32; off; off >>= 1) sum += __shfl_xor(sum, off, 64);
        float mu = sum * (1.0f / 192.0f);
        float dx = ax - mu, dy = ay - mu, dz = az - mu, dw = aw - mu;
        float vs = act ? (dx * dx + dy * dy + dz * dz + dw * dw) : 0.f;
        #pragma unroll
        for (int off = 32; off; off >>= 1) vs += __shfl_xor(vs, off, 64);
        float rstd = rsqrtf(vs * (1.0f / 192.0f) + 1e-9f);
        if (act) {
            float4 g = *(const float4*)&gamma[d0];
            float4 bb = *(const float4*)&beta[d0];
            float4 rv;
            rv.x = dx * rstd * g.x + bb.x;
            rv.y = dy * rstd * g.y + bb.y;
            rv.z = dz * rstd * g.z + bb.z;
            rv.w = dw * rstd * g.w + bb.w;
            *(float4*)&out[(size_t)row * 192 + d0] = rv;
        }
    }
}

// ---------------- launch ----------------
extern "C" void kernel_launch(void* const* d_in, const int* in_sizes, int n_in,
                              void* d_out, int out_size, void* d_ws, size_t ws_size,
                              hipStream_t stream) {
    const float* x        = (const float*)d_in[0];
    const float* mask0    = (const float*)d_in[1];
    const float* Wq       = (const float*)d_in[2];
    const float* Wk       = (const float*)d_in[3];
    const float* bk       = (const float*)d_in[4];
    const float* Wv       = (const float*)d_in[5];
    const float* bv       = (const float*)d_in[6];
    const float* Wo       = (const float*)d_in[7];
    const float* bo       = (const float*)d_in[8];
    const float* rwb      = (const float*)d_in[9];
    const float* rrb      = (const float*)d_in[10];
    const float* r_kernel = (const float*)d_in[11];
    const float* gamma    = (const float*)d_in[12];
    const float* beta     = (const float*)d_in[13];
    float* out = (float*)d_out;

    unsigned* QWt = (unsigned*)d_ws;                       // 196608 dwords
    unsigned* QRt = QWt + 196608;                          // 196608
    unsigned* Kpl = QRt + 196608;                          // 196608
    unsigned* Vpl = Kpl + 196608;                          // 196608
    uint4*    P   = (uint4*)(Vpl + 196608);                // 1048576 uint4 (16 MB)
    unsigned short* phiB = (unsigned short*)(P + 1048576); // 262144 ushorts
    unsigned* Whp = (unsigned*)(phiB + 262144);            // 27648 dwords

    k_wpack<<<288, 96, 0, stream>>>(Wq, Wk, Wv, Whp);
    k_pre<<<1664, 256, 0, stream>>>(x, Whp, bk, bv, rwb, rrb, r_kernel,
                                    QWt, QRt, Kpl, Vpl, phiB);
    k_attn<<<dim3(16, 16, 4), 256, 0, stream>>>(QWt, QRt, Kpl, Vpl, mask0, phiB, P);
    k_out<<<256, 256, 0, stream>>>(P, Wo, bo, x, gamma, beta, out);
}